// Round 11
// baseline (270.650 us; speedup 1.0000x reference)
//
#include <hip/hip_runtime.h>

// Fusedmax: out = sparsemax(prox_TV1D(x, alpha=1)) row-wise. B=4096, N=512, fp32.
//
// v11: v9's bidirectional structure (2 waves/row, 8192 waves, VALUBusy ~97% =
// issue-saturated) + v4's STATIC-INDEX step body (proven correct in v4, where
// it was neutral only because that regime was latency-bound at 46% busy).
// At 97% busy, issue slots = wall time, so the per-step bookkeeping v4 removed
// (++k, cntf+=1, dead k==N-1 check -- batch positions <= 510 by construction)
// now converts directly:
//   fast-path step = 10 slots: add, cmp/br, add, cmp/br, sub, sub, cmp/br x2
//   clamp body (branchy, v3-style -- 2 slots untaken beats 6 predicated):
//     vmin += (umin_t - lam) * rcp(cntb + J); km = b + J  (cnt exact integer
//     float; same values as (float)(k-k0+1) -- v4-verified arithmetic).
// Tail (positions >= 504, rare with STOPK) and end-phase: classic per-step
// form verbatim from v9/v10. Scalar flushes (segments avg 2-3 elems; v10
// proved float4-flush overhead nets zero). Stop rule, staging, stitch,
// Michelot sparsemax: v9 verbatim.

#define TVN 512
#define LAMBDA 1.0f
#define STOPK 257

__device__ __forceinline__ float wave_reduce_sum(float v) {
#pragma unroll
    for (int off = 32; off > 0; off >>= 1) v += __shfl_xor(v, off, 64);
    return v;
}

// One Condat step at position b + J (J compile-time), yn in W.
// Jump tests use cached tube bounds (bit-equal: vminl == vmin - lam).
#define STEP(W, J)                                                      \
    {                                                                   \
        const float t1 = (W) + umin;                                    \
        if (t1 < vminl) goto neg_jump;                                  \
        const float t2 = (W) + umax;                                    \
        if (t2 > vmaxl) goto pos_jump;                                  \
        umin = t1 - vmin;                                               \
        umax = t2 - vmax;                                               \
        if (umin >= lam) {                                              \
            vmin += (umin - lam) *                                      \
                    __builtin_amdgcn_rcpf(cntb + (float)(J));           \
            vminl = vmin - lam; umin = lam; km = b + (J);               \
        }                                                               \
        if (umax <= -lam) {                                             \
            vmax += (umax + lam) *                                      \
                    __builtin_amdgcn_rcpf(cntb + (float)(J));           \
            vmaxl = vmax + lam; umax = -lam; kp = b + (J);              \
        }                                                               \
    }

// v9's verified scan + early stop, with v4's static-index batch engine.
__device__ __forceinline__ void tv_scan_half(float* __restrict__ row) {
    const float lam = LAMBDA;
    const float yLast = row[TVN - 1];
    const float twolam = 2.0f * lam;
    int k = 0, k0 = 0, km = 0, kp = 0, b, nk;
    float vmin = row[0] - lam, vmax = row[0] + lam;
    float vminl = vmin - lam, vmaxl = vmax + lam;
    float umin = lam, umax = -lam;
    float cntb, ynk, yn;

    goto refill_from_k;

refill_from_k:                             // k, k0 valid; next position = k+1
    b = k + 1;
    cntb = (float)(k - k0 + 2);            // count at batch offset 0
    goto batch_check;

batch_check:                               // b = next position, cntb = b-k0+1
    if (b > TVN - 9) { k = b - 1; goto tail; }
    {
        // positions b..b+7, all <= 510 (end check not needed in-batch)
        const float w0 = row[b + 0], w1 = row[b + 1], w2 = row[b + 2], w3 = row[b + 3];
        const float w4 = row[b + 4], w5 = row[b + 5], w6 = row[b + 6], w7 = row[b + 7];
        STEP(w0, 0) STEP(w1, 1) STEP(w2, 2) STEP(w3, 3)
        STEP(w4, 4) STEP(w5, 5) STEP(w6, 6) STEP(w7, 7)
    }
    b += 8; cntb += 8.0f;
    goto batch_check;

neg_jump:                                  // flush [k0, km] = vmin, restart at km+1
    for (int i = k0; i <= km; ++i) row[i] = vmin;
    nk = km + 1;                           // <= TVN-1, untouched index
    if (nk >= STOPK) return;               // coverage [0, nk-1] ⊇ [0, 256]: done
    ynk = row[nk];
    k = k0 = km = kp = nk;
    vmin = ynk; vmax = ynk + twolam;
    vminl = vmin - lam; vmaxl = vmax + lam;
    umin = lam; umax = -lam;
    b = nk + 1; cntb = 2.0f;               // nk < 257 -> never end-phase here
    goto batch_check;

pos_jump:                                  // flush [k0, kp] = vmax, restart at kp+1
    for (int i = k0; i <= kp; ++i) row[i] = vmax;
    nk = kp + 1;
    if (nk >= STOPK) return;               // coverage [0, nk-1] ⊇ [0, 256]: done
    ynk = row[nk];
    k = k0 = km = kp = nk;
    vmax = ynk; vmin = ynk - twolam;
    vminl = vmin - lam; vmaxl = vmax + lam;
    umin = lam; umax = -lam;
    b = nk + 1; cntb = 2.0f;
    goto batch_check;

tail: {                                    // classic per-step with end checks
        float cntf = (float)(k - k0 + 1);
        for (;;) {
            yn = row[k + 1];
            if (yn + umin < vminl) goto neg_jump;
            if (yn + umax > vmaxl) goto pos_jump;
            ++k; cntf += 1.0f;
            umin += yn - vmin;
            umax += yn - vmax;
            if (umin >= lam) {
                vmin += (umin - lam) * __builtin_amdgcn_rcpf(cntf);
                vminl = vmin - lam; umin = lam; km = k;
            }
            if (umax <= -lam) {
                vmax += (umax + lam) * __builtin_amdgcn_rcpf(cntf);
                vmaxl = vmax + lam; umax = -lam; kp = k;
            }
            if (k == TVN - 1) goto end_phase;
        }
    }

end_phase: {
        // Reached only when no jump ever hit nk >= STOPK (giant tail segment):
        // run the verified full end phase to completion (no stop checks --
        // rewind may rewrite earlier indices; completion is the safe path).
        for (;;) {
            if (umin < 0.0f) {             // end-phase negative jump
                for (int i = k0; i <= km; ++i) row[i] = vmin;
                nk = km + 1;
                ynk = (nk > TVN - 1) ? yLast : row[nk];
                if (nk > TVN - 1) nk = TVN - 1;
                k = k0 = km = nk;
                vmin = ynk;
                vminl = vmin - lam;        // vmax/vmaxl unchanged (reference)
                umin = lam;
                umax = ynk + lam - vmax;   // old vmax
                if (k == TVN - 1) continue;
                goto refill_from_k;
            } else if (umax > 0.0f) {      // end-phase positive jump
                for (int i = k0; i <= kp; ++i) row[i] = vmax;
                nk = kp + 1;
                ynk = (nk > TVN - 1) ? yLast : row[nk];
                if (nk > TVN - 1) nk = TVN - 1;
                k = k0 = kp = nk;
                vmax = ynk;
                vmaxl = vmax + lam;        // vmin/vminl unchanged (reference)
                umax = -lam;
                umin = ynk - lam - vmin;   // old vmin
                if (k == TVN - 1) continue;
                goto refill_from_k;
            } else {                       // finish
                const float v = vmin + umin / (float)(k - k0 + 1);
                for (int i = k0; i < TVN; ++i) row[i] = v;
                return;
            }
        }
    }
}

__global__ __launch_bounds__(128) void fusedmax_kernel(const float* __restrict__ xin,
                                                       float* __restrict__ out) {
    __shared__ alignas(16) float rowF[TVN + 8];   // forward buffer
    __shared__ alignas(16) float rowR[TVN + 8];   // reversed buffer

    const int t = threadIdx.x;                 // 0..127
    const int w = t >> 6;                      // wave id: 0 = forward, 1 = backward
    const int lane = t & 63;
    const long long r = blockIdx.x;

    // ---- stage: wave 0 -> rowF coalesced; wave 1 -> rowR reversed ----
    const float4* __restrict__ g4 = (const float4*)(xin + r * TVN);
    if (w == 0) {
        float4* s4 = (float4*)rowF;
        s4[lane] = g4[lane];
        s4[lane + 64] = g4[lane + 64];
        if (lane < 8) rowF[TVN + lane] = 0.0f;
    } else {
        float4 a = g4[lane];                   // elems 4*lane .. 4*lane+3
        float4 b = g4[lane + 64];              // elems 256+4*lane ..
        const int ba = 511 - 4 * lane;
        rowR[ba] = a.x; rowR[ba - 1] = a.y; rowR[ba - 2] = a.z; rowR[ba - 3] = a.w;
        const int bb = 255 - 4 * lane;
        rowR[bb] = b.x; rowR[bb - 1] = b.y; rowR[bb - 2] = b.z; rowR[bb - 3] = b.w;
        if (lane < 8) rowR[TVN + lane] = 0.0f;
    }
    __syncthreads();

    // ---- two independent half-scans (lane 0 of each wave) ----
    if (lane == 0) tv_scan_half(w ? rowR : rowF);
    __syncthreads();

    // ---- stitched gather: i<=256 from rowF, i>=257 from rowR[511-i] ----
    float v[8];
#pragma unroll
    for (int j = 0; j < 4; ++j) v[j] = rowF[4 * lane + j];          // 0..255
    {
        const int i0 = 256 + 4 * lane;
        v[4] = (i0 == 256) ? rowF[256] : rowR[511 - i0];
        v[5] = rowR[511 - (i0 + 1)];
        v[6] = rowR[511 - (i0 + 2)];
        v[7] = rowR[511 - (i0 + 3)];
    }

    // ---- sparsemax via Michelot fixed point (exact tau, no sort) ----
    float ls = v[0] + v[1] + v[2] + v[3] + v[4] + v[5] + v[6] + v[7];
    float S = wave_reduce_sum(ls);
    float tau = (S - 1.0f) * (1.0f / (float)TVN);   // support = all
    int cprev = TVN;
#pragma unroll 1
    for (int it = 0; it < 64; ++it) {
        float s = 0.0f, c = 0.0f;
#pragma unroll
        for (int j = 0; j < 8; ++j) {
            if (v[j] > tau) { s += v[j]; c += 1.0f; }
        }
        s = wave_reduce_sum(s);
        c = wave_reduce_sum(c);               // >= 1 always (tau < max)
        tau = (s - 1.0f) / c;
        int ci = (int)c;
        if (ci == cprev) break;               // support stabilized -> tau exact
        cprev = ci;
    }

    // ---- each wave writes its half of the row ----
    float4 o;
    if (w == 0) {
        o.x = fmaxf(v[0] - tau, 0.0f);
        o.y = fmaxf(v[1] - tau, 0.0f);
        o.z = fmaxf(v[2] - tau, 0.0f);
        o.w = fmaxf(v[3] - tau, 0.0f);
    } else {
        o.x = fmaxf(v[4] - tau, 0.0f);
        o.y = fmaxf(v[5] - tau, 0.0f);
        o.z = fmaxf(v[6] - tau, 0.0f);
        o.w = fmaxf(v[7] - tau, 0.0f);
    }
    float4* __restrict__ o4 = (float4*)(out + r * TVN);
    o4[lane + ((w == 0) ? 0 : 64)] = o;
}

extern "C" void kernel_launch(void* const* d_in, const int* in_sizes, int n_in,
                              void* d_out, int out_size, void* d_ws, size_t ws_size,
                              hipStream_t stream) {
    const float* x = (const float*)d_in[0];
    float* out = (float*)d_out;
    const int rows = in_sizes[0] / TVN;       // 4096
    fusedmax_kernel<<<dim3(rows), dim3(128), 0, stream>>>(x, out);
}